// Round 8
// baseline (299.018 us; speedup 1.0000x reference)
//
#include <hip/hip_runtime.h>

// CorrelationPyramid on MI355X — round 12: r11 (transpose + gather-free proj)
// with the to_nhwc chunk-indexing bug fixed.
//
// r11 NaN cause: copy-out decomposed 1024 chunks as px=m>>3, c8=(m&7)*8 —
// 64 channels/pixel and px up to 127 (LDS tile has 64 rows): OOB reads +
// garbage writes into other blocks' NHWC rows. Correct: 16 chunks/pixel,
// px=m>>4, c8=(m&15)*8.
//
// Pipeline (4 dispatches):
//   0) prep_weights : one-shot fp32 -> f16 of the 64x128 projection matrix.
//   1) to_nhwc      : NCHW fp32 -> NHWC f16 streaming transpose (LDS-tiled,
//                     XOR swizzle, coalesced writes). BW-bound by design.
//   2) proj_pool    : gather-free: 4x16-B direct NHWC loads per lane;
//                     LDS 18.4 KB -> 6 blocks/CU; MFMA + in-block pooling
//                     pyramid, emits normalized f16 L0-L3.
//   3) corr_all     : unchanged (one dispatch, all levels).

typedef _Float16 f16;
typedef _Float16 f16x4 __attribute__((ext_vector_type(4)));
typedef _Float16 f16x8 __attribute__((ext_vector_type(8)));
typedef float f32x4 __attribute__((ext_vector_type(4)));

#define EPSN 1e-12f

// ---------------- one-shot weight fp32 -> f16 ----------------
__global__ __launch_bounds__(256) void prep_weights(
    const float* __restrict__ wt, f16* __restrict__ wh) {
  int gid = blockIdx.x * 256 + threadIdx.x;   // 2048 threads x 4 elems = 8192
  float4 w = *(const float4*)(wt + gid * 4);
  f16x4 h;
  h[0] = (f16)w.x; h[1] = (f16)w.y; h[2] = (f16)w.z; h[3] = (f16)w.w;
  *(f16x4*)(wh + gid * 4) = h;
}

// ---------------- NCHW fp32 -> NHWC f16 transpose ----------------
// Block = 64 linear pixels x 128 channels. Read: 16 lanes cover one
// channel's 64 px = 256-B contiguous segment, 4 channels per wave instr.
// LDS [px][136 f16] with cx = c ^ (((px>>2)&7)<<4) swizzle (write & read
// agree; keeps 8-channel runs contiguous and 16B-aligned).
// Write: f16x8 chunks; 16 chunks per pixel (128 ch): px=m>>4, c8=(m&15)*8.
__global__ __launch_bounds__(256, 4) void to_nhwc(
    const float* __restrict__ xq, const float* __restrict__ xv,
    f16* __restrict__ xo, int P) {
  __shared__ f16 ls[64 * 136];   // 17,408 B

  int pb = blockIdx.x;
  int bid = (pb & 7) * 500 + (pb >> 3);   // XCD-contiguous (same map as proj)
  int img = bid / 400;
  int poff = (bid - img * 400) * 64;
  const float* src = (img < 2) ? (xq + (size_t)img * 128 * P)
                               : (xv + (size_t)(img - 2) * 128 * P);

  int tid = threadIdx.x;
  int c0 = tid >> 4;            // 0..15
  int px4 = (tid & 15) * 4;     // 0..60
  int swz = ((px4 >> 2) & 7) << 4;
#pragma unroll
  for (int i = 0; i < 8; ++i) {
    int c = c0 + 16 * i;
    float4 v = *(const float4*)(src + (size_t)c * P + poff + px4);
    int cx = c ^ swz;
    ls[(px4 + 0) * 136 + cx] = (f16)v.x;
    ls[(px4 + 1) * 136 + cx] = (f16)v.y;
    ls[(px4 + 2) * 136 + cx] = (f16)v.z;
    ls[(px4 + 3) * 136 + cx] = (f16)v.w;
  }
  __syncthreads();

  size_t ob = ((size_t)img * P + poff) * 128;
#pragma unroll
  for (int j = 0; j < 4; ++j) {
    int m = tid + 256 * j;      // 0..1023 chunks of 8 f16 (16 per pixel)
    int px = m >> 4;            // 0..63
    int c8 = (m & 15) * 8;      // 0..120
    int cx8 = c8 ^ (((px >> 2) & 7) << 4);
    f16x8 h = *(const f16x8*)(ls + px * 136 + cx8);
    *(f16x8*)(xo + ob + (size_t)px * 128 + c8) = h;
  }
}

// ---------------- projection + pyramid pooling (NHWC f16 input) -------------
// Block = 256 threads = 4 waves = one 8x8 pixel tile of one image.
// LDS: f16 wsh[64][136] (weights; later reused as fp32 acc[64 px][68]) +
//      float l3buf[64][4]. 18,432 B total -> 6 blocks/CU.
#define LROW 68
#define WS 136

__global__ __launch_bounds__(256, 6) void proj_pool(
    const f16* __restrict__ xh, const f16* __restrict__ wh,
    const float* __restrict__ bias,
    f16* __restrict__ h0, f16* __restrict__ h1,
    f16* __restrict__ h2, f16* __restrict__ h3, int P) {
  __shared__ f16 wsh[64 * WS];       // 17,408 B
  __shared__ float l3buf[64 * 4];    // 1,024 B
  float* accbuf = (float*)wsh;       // 64 px x 68 floats (aliased)

  int pb = blockIdx.x;
  int bid = (pb & 7) * 500 + (pb >> 3);   // XCD-contiguous

  int img = bid / 400;               // 10 images: 0,1 = query; 2..9 = values
  int t = bid - img * 400;           // 20x20 tiles of 8x8 px
  int ty = t / 20, tx = t - ty * 20;
  int py0 = ty * 8, px0 = tx * 8;

  int tid = threadIdx.x;
  int lane = tid & 63;
  int wv = tid >> 6;
  int cl = lane & 15;
  int quad = lane >> 4;

  // ---- stage weights: coalesced f16x8, stride-136 rows ----
  for (int m = tid; m < 1024; m += 256) {
    int o = m >> 4, kk = (m & 15) * 8;
    *(f16x8*)(wsh + o * WS + kk) = *(const f16x8*)(wh + o * 128 + kk);
  }

  // ---- B fragments: 4 direct 16-B loads from NHWC f16 (L2-resident) ----
  int pxl = wv * 16 + cl;                  // tile-local pixel this lane owns
  int gp = (py0 + (pxl >> 3)) * 160 + px0 + (pxl & 7);
  const f16* xp = xh + ((size_t)img * P + gp) * 128 + quad * 8;
  f16x8 bfr[4];
#pragma unroll
  for (int kc = 0; kc < 4; ++kc) bfr[kc] = *(const f16x8*)(xp + kc * 32);

  __syncthreads();   // #1: weights staged (loads above overlap the barrier)

  f32x4 acc[4];
#pragma unroll
  for (int m = 0; m < 4; ++m) acc[m] = (f32x4)0.f;

#pragma unroll
  for (int kc = 0; kc < 4; ++kc) {
    f16x8 afr[4];
#pragma unroll
    for (int mt = 0; mt < 4; ++mt)
      afr[mt] = *(const f16x8*)(wsh + (mt * 16 + cl) * WS + kc * 32 + quad * 8);
#pragma unroll
    for (int mt = 0; mt < 4; ++mt)
      acc[mt] = __builtin_amdgcn_mfma_f32_16x16x32_f16(afr[mt], bfr[kc], acc[mt], 0, 0, 0);
  }

  float4 bi[4];
#pragma unroll
  for (int mt = 0; mt < 4; ++mt) bi[mt] = *(const float4*)(bias + mt * 16 + quad * 4);

  __syncthreads();   // #2: all wsh reads done before accbuf overwrite

  // ---- epilogue A: bias, stash un-normalized acc, L0 normalize + store ----
  float ss = 0.f;
#pragma unroll
  for (int mt = 0; mt < 4; ++mt) {
    acc[mt][0] += bi[mt].x;
    acc[mt][1] += bi[mt].y;
    acc[mt][2] += bi[mt].z;
    acc[mt][3] += bi[mt].w;
    *(float4*)(accbuf + pxl * LROW + mt * 16 + quad * 4) =
        make_float4(acc[mt][0], acc[mt][1], acc[mt][2], acc[mt][3]);
#pragma unroll
    for (int r = 0; r < 4; ++r) ss = fmaf(acc[mt][r], acc[mt][r], ss);
  }
  ss += __shfl_xor(ss, 16, 64);
  ss += __shfl_xor(ss, 32, 64);
  float s = 1.0f / fmaxf(sqrtf(ss), EPSN);
  {
    size_t base = ((size_t)img * P + gp) * 64;
#pragma unroll
    for (int mt = 0; mt < 4; ++mt) {
      f16x4 hn;
      hn[0] = (f16)(acc[mt][0] * s);
      hn[1] = (f16)(acc[mt][1] * s);
      hn[2] = (f16)(acc[mt][2] * s);
      hn[3] = (f16)(acc[mt][3] * s);
      *(f16x4*)(h0 + base + mt * 16 + quad * 4) = hn;
    }
  }
  __syncthreads();   // #3: accbuf visible to pool phase

  // ---- pool phase ----
  int r2 = wv >> 1, c2 = wv & 1;
  int g = quad, c4 = cl;
  int r1 = 2 * r2 + (g >> 1), c1 = 2 * c2 + (g & 1);
  int p00 = (2 * r1) * 8 + 2 * c1;

  float4 s00 = *(const float4*)(accbuf + p00 * LROW + c4 * 4);
  float4 s01 = *(const float4*)(accbuf + (p00 + 1) * LROW + c4 * 4);
  float4 s10 = *(const float4*)(accbuf + (p00 + 8) * LROW + c4 * 4);
  float4 s11 = *(const float4*)(accbuf + (p00 + 9) * LROW + c4 * 4);
  float4 v1;
  v1.x = 0.25f * (s00.x + s01.x + s10.x + s11.x);
  v1.y = 0.25f * (s00.y + s01.y + s10.y + s11.y);
  v1.z = 0.25f * (s00.z + s01.z + s10.z + s11.z);
  v1.w = 0.25f * (s00.w + s01.w + s10.w + s11.w);

  {
    float s1 = fmaf(v1.x, v1.x, fmaf(v1.y, v1.y, fmaf(v1.z, v1.z, v1.w * v1.w)));
    s1 += __shfl_xor(s1, 1, 64);
    s1 += __shfl_xor(s1, 2, 64);
    s1 += __shfl_xor(s1, 4, 64);
    s1 += __shfl_xor(s1, 8, 64);
    float sc = 1.0f / fmaxf(sqrtf(s1), EPSN);
    f16x4 h;
    h[0] = (f16)(v1.x * sc); h[1] = (f16)(v1.y * sc);
    h[2] = (f16)(v1.z * sc); h[3] = (f16)(v1.w * sc);
    *(f16x4*)(h1 + ((size_t)(img * 80 + ty * 4 + r1) * 80 + tx * 4 + c1) * 64 + c4 * 4) = h;
  }

  float4 q2v;
  q2v.x = v1.x + __shfl_xor(v1.x, 16, 64);
  q2v.y = v1.y + __shfl_xor(v1.y, 16, 64);
  q2v.z = v1.z + __shfl_xor(v1.z, 16, 64);
  q2v.w = v1.w + __shfl_xor(v1.w, 16, 64);
  q2v.x += __shfl_xor(q2v.x, 32, 64);
  q2v.y += __shfl_xor(q2v.y, 32, 64);
  q2v.z += __shfl_xor(q2v.z, 32, 64);
  q2v.w += __shfl_xor(q2v.w, 32, 64);
  q2v.x *= 0.25f; q2v.y *= 0.25f; q2v.z *= 0.25f; q2v.w *= 0.25f;

  {
    float s2 = fmaf(q2v.x, q2v.x, fmaf(q2v.y, q2v.y, fmaf(q2v.z, q2v.z, q2v.w * q2v.w)));
    s2 += __shfl_xor(s2, 1, 64);
    s2 += __shfl_xor(s2, 2, 64);
    s2 += __shfl_xor(s2, 4, 64);
    s2 += __shfl_xor(s2, 8, 64);
    float sc = 1.0f / fmaxf(sqrtf(s2), EPSN);
    if (g == 0) {
      f16x4 h;
      h[0] = (f16)(q2v.x * sc); h[1] = (f16)(q2v.y * sc);
      h[2] = (f16)(q2v.z * sc); h[3] = (f16)(q2v.w * sc);
      *(f16x4*)(h2 + ((size_t)(img * 40 + ty * 2 + r2) * 40 + tx * 2 + c2) * 64 + c4 * 4) = h;
      *(float4*)(l3buf + (wv * 16 + c4) * 4) = q2v;
    }
  }
  __syncthreads();   // #4: l3buf visible

  if (tid < 16) {
    float4 a0 = *(const float4*)(l3buf + (0 * 16 + tid) * 4);
    float4 a1 = *(const float4*)(l3buf + (1 * 16 + tid) * 4);
    float4 a2 = *(const float4*)(l3buf + (2 * 16 + tid) * 4);
    float4 a3 = *(const float4*)(l3buf + (3 * 16 + tid) * 4);
    float4 q3;
    q3.x = 0.25f * (a0.x + a1.x + a2.x + a3.x);
    q3.y = 0.25f * (a0.y + a1.y + a2.y + a3.y);
    q3.z = 0.25f * (a0.z + a1.z + a2.z + a3.z);
    q3.w = 0.25f * (a0.w + a1.w + a2.w + a3.w);
    float s3 = fmaf(q3.x, q3.x, fmaf(q3.y, q3.y, fmaf(q3.z, q3.z, q3.w * q3.w)));
    s3 += __shfl_xor(s3, 1, 64);
    s3 += __shfl_xor(s3, 2, 64);
    s3 += __shfl_xor(s3, 4, 64);
    s3 += __shfl_xor(s3, 8, 64);
    float sc = 1.0f / fmaxf(sqrtf(s3), EPSN);
    f16x4 h;
    h[0] = (f16)(q3.x * sc); h[1] = (f16)(q3.y * sc);
    h[2] = (f16)(q3.z * sc); h[3] = (f16)(q3.w * sc);
    *(f16x4*)(h3 + ((size_t)(img * 20 + ty) * 20 + tx) * 64 + tid * 4) = h;
  }
}

// ---------------- correlation: one wave per (bn, h, w-tile) ----------------
// (unchanged from round 10)
template <int R>
__device__ __forceinline__ void corr_level(
    const f16* __restrict__ qh, const f16* __restrict__ vh,
    float* __restrict__ out, int H, int W, int T, int blk, float* lw) {
  constexpr int D = 2 * R + 1, DD = D * D;
  constexpr int PS = (DD + 3) & ~3;           // padded per-pixel stride
  int bn = blk & 7;                      // 8 bn values -> 8 XCDs (heuristic)
  int wv = threadIdx.x >> 6;
  int widx = (blk >> 3) * 4 + wv;        // [0, H*T)
  int h = widx / T;
  int wt = widx - h * T;
  int lane = threadIdx.x & 63;
  int cl = lane & 15, quad = lane >> 4;
  int b = bn >> 2;
  int w0 = wt * 16;
  float* lwv = lw + wv * 16 * PS;        // wave-private region

  int ap = w0 + cl; if (ap >= W) ap = W - 1;   // clamp partial tile
  const f16* qp = qh + ((size_t)(b * H + h) * W + ap) * 64 + quad * 8;
  f16x8 a0 = *(const f16x8*)qp;
  f16x8 a1 = *(const f16x8*)(qp + 32);

  int c0 = w0 - R + cl; if (c0 < 0) c0 += W; if (c0 >= W) c0 -= W;
  int c1 = w0 + R + cl; if (c1 >= W) c1 -= W;
  int b0off = c0 * 64 + quad * 8;
  int b1off = c1 * 64 + quad * 8;

  int rbase = quad * 4;
  int base_dxi = rbase - cl + ((quad < 2) ? 2 * R : 0);

  for (int dyi = 0; dyi < D; ++dyi) {
    int h2 = h - dyi + R; if (h2 < 0) h2 += H; else if (h2 >= H) h2 -= H;
    const f16* vrow = vh + ((size_t)(bn * H + h2) * W) * 64;
    f16x8 b0a = *(const f16x8*)(vrow + b0off);
    f16x8 b0b = *(const f16x8*)(vrow + b0off + 32);
    f16x8 b1a = *(const f16x8*)(vrow + b1off);
    f16x8 b1b = *(const f16x8*)(vrow + b1off + 32);
    f32x4 A0 = __builtin_amdgcn_mfma_f32_16x16x32_f16(a0, b0a, (f32x4)0.f, 0, 0, 0);
    A0 = __builtin_amdgcn_mfma_f32_16x16x32_f16(a1, b0b, A0, 0, 0, 0);
    f32x4 A1 = __builtin_amdgcn_mfma_f32_16x16x32_f16(a0, b1a, (f32x4)0.f, 0, 0, 0);
    A1 = __builtin_amdgcn_mfma_f32_16x16x32_f16(a1, b1b, A1, 0, 0, 0);
#pragma unroll
    for (int rr = 0; rr < 4; ++rr) {
      int dxi = base_dxi + rr;
      float val = (quad < 2) ? A0[rr] : A1[rr];
      if ((unsigned)dxi <= (unsigned)(2 * R))
        lwv[(rbase + rr) * PS + dyi * D + dxi] = val;
    }
  }

  int vp = W - w0; if (vp > 16) vp = 16;
  float* ob = out + ((size_t)(bn * H + h) * W + w0) * DD;
  int tot = vp * DD;
  for (int gg = lane; gg < tot; gg += 64) {
    int pl = gg / DD;                     // constexpr divisor -> magic mul
    int rem = gg - pl * DD;
    ob[gg] = lwv[pl * PS + rem];
  }
}

__global__ __launch_bounds__(256, 6) void corr_all(
    const f16* __restrict__ q0, const f16* __restrict__ v0,
    const f16* __restrict__ q1, const f16* __restrict__ v1,
    const f16* __restrict__ q2, const f16* __restrict__ v2,
    const f16* __restrict__ q3, const f16* __restrict__ v3,
    float* __restrict__ o0, float* __restrict__ o1,
    float* __restrict__ o2, float* __restrict__ o3) {
  __shared__ float lw[4 * 16 * 84];   // max (R=4) wave-private staging, 21.5 KB
  int blk = blockIdx.x;
  if (blk < 3200)      corr_level<4>(q0, v0, o0, 160, 160, 10, blk, lw);
  else if (blk < 4000) corr_level<2>(q1, v1, o1, 80, 80, 5, blk - 3200, lw);
  else if (blk < 4240) corr_level<1>(q2, v2, o2, 40, 40, 3, blk - 4000, lw);
  else                 corr_level<1>(q3, v3, o3, 20, 20, 2, blk - 4240, lw);
}

extern "C" void kernel_launch(void* const* d_in, const int* in_sizes, int n_in,
                              void* d_out, int out_size, void* d_ws, size_t ws_size,
                              hipStream_t stream) {
  const float* query  = (const float*)d_in[0];   // [2,128,160,160]
  const float* values = (const float*)d_in[1];   // [2,4,128,160,160]
  const float* pw     = (const float*)d_in[2];   // [64,128]
  const float* pb     = (const float*)d_in[3];   // [64]
  float* out = (float*)d_out;
  float* ws  = (float*)d_ws;

  const int B = 2, N = 4;
  const int P0 = 160 * 160;

  // Workspace layout (f16): levels 0-3 ({q_b0,q_b1,v_0..v_7} each), converted
  // weights, then the NHWC f16 input mirror.
  f16* h0 = (f16*)ws;
  f16* h1 = h0 + (size_t)10 * P0 * 64;
  f16* h2 = h1 + (size_t)10 * (P0 / 4) * 64;
  f16* h3 = h2 + (size_t)10 * (P0 / 16) * 64;
  f16* wh = h3 + (size_t)10 * (P0 / 64) * 64;   // 8192 f16
  f16* xh = wh + 8192;                          // 10*P0*128 f16 = 65.5 MB

  f16* q0h = h0;             f16* v0h = h0 + (size_t)2 * P0 * 64;
  f16* qh1 = h1;             f16* vh1 = h1 + (size_t)2 * (P0 / 4) * 64;
  f16* qh2 = h2;             f16* vh2 = h2 + (size_t)2 * (P0 / 16) * 64;
  f16* qh3 = h3;             f16* vh3 = h3 + (size_t)2 * (P0 / 64) * 64;

  // 0) one-shot weight conversion
  prep_weights<<<8, 256, 0, stream>>>(pw, wh);

  // 1) NCHW fp32 -> NHWC f16 transpose (streaming, BW-bound)
  to_nhwc<<<4000, 256, 0, stream>>>(query, values, xh, P0);

  // 2) fused projection + pooling pyramid (gather-free, 6 blocks/CU)
  proj_pool<<<4000, 256, 0, stream>>>(xh, wh, pb, h0, h1, h2, h3, P0);

  // 3) correlation — ONE dispatch, all four levels
  float* out0 = out;
  float* out1 = out0 + (size_t)B * N * P0 * 81;
  float* out2 = out1 + (size_t)B * N * (P0 / 4) * 25;
  float* out3 = out2 + (size_t)B * N * (P0 / 16) * 9;
  corr_all<<<4320, 256, 0, stream>>>(q0h, v0h, qh1, vh1, qh2, vh2, qh3, vh3,
                                     out0, out1, out2, out3);
}